// Round 8
// baseline (105.171 us; speedup 1.0000x reference)
//
#include <hip/hip_runtime.h>

#define MAXP 1048576           // static pair bound (MAX_PAIRS)
#define NATOMS 8192
#define D2_CUT 0x1.8ffffep+4f  // fl(sqrt(s))<5  <=>  s < 25-2^-19
#define CINV 0.175f            // 7/40: 7^3=343 cells, width 5.714 > 5.0004 (conservative)
#define CAP 192                // max hits/row (avg ~67)

// d_ws layout (float offsets). Total 46080 floats = 180 KB (below proven 210 KB).
#define W_SORTPOS 0            // float4[8192] cell-sorted (x,y,z,sq)
#define W_SORTID  32768        // u16[8192] sorted slot -> original atom id
#define W_ROWCNT  36864        // int[8192] per-row hit counts
#define W_GRPSUM  45056        // int[128] per-64-row-group sums (padded to 512)
#define W_CELLOFF 45568        // int[344], padded to 512

__device__ __forceinline__ float sq3_nc(float x, float y, float z) {
#pragma clang fp contract(off)
  float a = x * x;
  float b = y * y;
  float c = z * z;
  return (a + b) + c;
}

// mask per _pairwise_dist: sq_i + sq_j - 2*(x @ x.T); BLAS K=3 FMA chain (bit-exact, proven)
__device__ __forceinline__ float d2_gram(float xi, float yi, float zi, float sqi,
                                         float xj, float yj, float zj, float sqj) {
#pragma clang fp contract(off)
  float g = xi * xj;
  g = __builtin_fmaf(yi, yj, g);
  g = __builtin_fmaf(zi, zj, g);
  float t = sqi + sqj;
  float d2 = t - 2.0f * g;
  return d2;
}

__device__ __forceinline__ float d2_direct(float xi, float yi, float zi,
                                           float xj, float yj, float zj) {
#pragma clang fp contract(off)
  float dx = xj - xi;
  float dy = yj - yi;
  float dz = zj - zi;
  float a = dx * dx;
  float b = dy * dy;
  float c = dz * dz;
  return (a + b) + c;
}

__device__ __forceinline__ int cellco(float v) {
  int c = (int)(v * CINV);
  return c < 0 ? 0 : (c > 6 ? 6 : c);
}

// K0: FUSED zero + prep. Block 0: r7-proven single-block bin+scan+scatter.
// Blocks 1..63: zero the 16.8 MB output (runs in prep's shadow). Block 1 also
// zeros grpsum. Grid 64 x 1024.
__global__ __launch_bounds__(1024) void nl_prep(const float* __restrict__ pos,
                                                float* __restrict__ out,
                                                float* __restrict__ ws) {
  const int tid = threadIdx.x;
  if (blockIdx.x != 0) {
    float4* o4 = (float4*)out;  // 4*MAXP floats = 1,048,576 float4
    const int b = blockIdx.x - 1;  // 0..62
    for (int i = b * 1024 + tid; i < 1048576; i += 63 * 1024)
      o4[i] = make_float4(0.f, 0.f, 0.f, 0.f);
    if (blockIdx.x == 1 && tid < 512) ((int*)(ws + W_GRPSUM))[tid] = 0;
    return;
  }

  __shared__ int hcnt[343];
  __shared__ int hoff[344];
  __shared__ int hcur[343];
  __shared__ int s[512];
  if (tid < 343) { hcnt[tid] = 0; hcur[tid] = 0; }
  __syncthreads();

  float x[8], y[8], z[8];
  int cl[8];
#pragma unroll
  for (int k = 0; k < 8; ++k) {
    int a = tid + k * 1024;
    x[k] = pos[3 * a]; y[k] = pos[3 * a + 1]; z[k] = pos[3 * a + 2];
    cl[k] = cellco(x[k]) + 7 * cellco(y[k]) + 49 * cellco(z[k]);
    atomicAdd(&hcnt[cl[k]], 1);
  }
  __syncthreads();

  if (tid < 512) s[tid] = (tid < 343) ? hcnt[tid] : 0;
  __syncthreads();
  for (int off = 1; off < 512; off <<= 1) {
    int v = (tid < 512 && tid >= off) ? s[tid - off] : 0;
    __syncthreads();
    if (tid < 512) s[tid] += v;
    __syncthreads();
  }
  if (tid < 343) hoff[tid] = (tid == 0) ? 0 : s[tid - 1];
  if (tid == 343) hoff[343] = NATOMS;
  __syncthreads();
  if (tid < 344) ((int*)(ws + W_CELLOFF))[tid] = hoff[tid];

  unsigned short* sortid = (unsigned short*)(ws + W_SORTID);
  float4* sortpos = (float4*)(ws + W_SORTPOS);
#pragma unroll
  for (int k = 0; k < 8; ++k) {
    int slot = hoff[cl[k]] + atomicAdd(&hcur[cl[k]], 1);
    sortid[slot] = (unsigned short)(tid + k * 1024);
    sortpos[slot] = make_float4(x[k], y[k], z[k], sq3_nc(x[k], y[k], z[k]));
  }
}

// K1: COUNT (r7-proven hot loop). One wave per sorted slot, 8 waves/SIMD.
// Lane 0 writes rowcnt[rid] AND accumulates the 64-row group sum (replaces the
// separate scan kernel). Self always predicates true -> cnt-1.
__global__ __launch_bounds__(256, 8) void nl_count(float* __restrict__ ws) {
  const int lane = threadIdx.x & 63;
  const int wave = threadIdx.x >> 6;
  const int slot = blockIdx.x * 4 + wave;  // sorted slot 0..8191

  const float4* __restrict__ sp4 = (const float4*)(ws + W_SORTPOS);
  const unsigned short* __restrict__ sid = (const unsigned short*)(ws + W_SORTID);
  const int* __restrict__ celloff = (const int*)(ws + W_CELLOFF);
  int* rowcnt = (int*)(ws + W_ROWCNT);
  int* grpsum = (int*)(ws + W_GRPSUM);

  const float4 pi = sp4[slot];  // bit-identical to pos-derived (x,y,z,sq)
  int cx = cellco(pi.x), cy = cellco(pi.y), cz = cellco(pi.z);
  int x0 = max(cx - 1, 0), x1 = min(cx + 1, 6);
  int y0 = max(cy - 1, 0), y1 = min(cy + 1, 6);
  int z0 = max(cz - 1, 0), z1 = min(cz + 1, 6);

  int cnt = 0;
  for (int icz = z0; icz <= z1; ++icz)
    for (int icy = y0; icy <= y1; ++icy) {
      int cb = 7 * icy + 49 * icz;
      int st = celloff[cb + x0];
      int en = celloff[cb + x1 + 1];
      for (int bb = st; bb < en; bb += 64) {
        int t = bb + lane;
        bool v = t < en;
        int t2 = v ? t : (en - 1);  // clamp: valid slot; pred killed by v
        float4 p = sp4[t2];
        float d2 = d2_gram(pi.x, pi.y, pi.z, pi.w, p.x, p.y, p.z, p.w);
        cnt += (v && d2 < D2_CUT) ? 1 : 0;
      }
    }
  for (int off = 32; off > 0; off >>= 1) cnt += __shfl_down(cnt, off, 64);
  if (lane == 0) {
    const int rid = sid[slot];
    rowcnt[rid] = cnt - 1;                          // remove self-pair
    atomicAdd(&grpsum[rid >> 6], cnt - 1);          // 64-row group partial
  }
}

// K2: WRITE (r7-proven bitmap path). Row offset computed INLINE from
// grpsum + rowcnt (== old exclusive scan, no extra kernel):
//   ro = sum_{g < rid>>6} grpsum[g] + sum_{t in [rid&~63, rid)} rowcnt[t]
__global__ __launch_bounds__(256, 8) void nl_write(const float* __restrict__ pos,
                                                   float* __restrict__ out,
                                                   const float* __restrict__ ws) {
  __shared__ unsigned int bmap[4][256];    // 8192 bits per wave (wave-private)
  __shared__ unsigned short stj[4][CAP];   // ascending j-list per wave
  const int lane = threadIdx.x & 63;
  const int wave = threadIdx.x >> 6;
  const int slot = blockIdx.x * 4 + wave;  // sorted slot 0..8191

  const float4* __restrict__ sp4 = (const float4*)(ws + W_SORTPOS);
  const unsigned short* __restrict__ sid = (const unsigned short*)(ws + W_SORTID);
  const int* __restrict__ celloff = (const int*)(ws + W_CELLOFF);
  const int* __restrict__ rowcnt = (const int*)(ws + W_ROWCNT);
  const int* __restrict__ grpsum = (const int*)(ws + W_GRPSUM);

#pragma unroll
  for (int q = 0; q < 4; ++q) bmap[wave][lane + 64 * q] = 0u;

  const float4 pi = sp4[slot];
  const int rid = sid[slot];

  // inline exclusive row offset (replaces rowoff[] / scan kernel)
  const int G = rid >> 6;
  int pre = ((lane < G) ? grpsum[lane] : 0) +
            ((lane + 64 < G) ? grpsum[lane + 64] : 0) +
            ((lane < (rid & 63)) ? rowcnt[(rid & ~63) + lane] : 0);
  for (int off = 32; off > 0; off >>= 1) pre += __shfl_down(pre, off, 64);
  const int ro = __shfl(pre, 0, 64);

  int cx = cellco(pi.x), cy = cellco(pi.y), cz = cellco(pi.z);
  int x0 = max(cx - 1, 0), x1 = min(cx + 1, 6);
  int y0 = max(cy - 1, 0), y1 = min(cy + 1, 6);
  int z0 = max(cz - 1, 0), z1 = min(cz + 1, 6);

  for (int icz = z0; icz <= z1; ++icz)
    for (int icy = y0; icy <= y1; ++icy) {
      int cb = 7 * icy + 49 * icz;
      int st = celloff[cb + x0];
      int en = celloff[cb + x1 + 1];
      for (int bb = st; bb < en; bb += 64) {
        int t = bb + lane;
        bool v = t < en;
        int t2 = v ? t : (en - 1);  // identical clamp as nl_count
        float4 p = sp4[t2];
        int jd = sid[t2];
        float d2 = d2_gram(pi.x, pi.y, pi.z, pi.w, p.x, p.y, p.z, p.w);
        if (v && d2 < D2_CUT)
          atomicOr(&bmap[wave][jd >> 5], 1u << (jd & 31));
      }
    }
  if (lane == 0)  // self always marked; clear it
    atomicAnd(&bmap[wave][rid >> 5], ~(1u << (rid & 31)));

  // extract in ascending j: 4 segments of 64 words; popcount prefix (proven)
  int ktot = 0;
#pragma unroll
  for (int seg = 0; seg < 4; ++seg) {
    int w = seg * 64 + lane;
    unsigned bits = bmap[wave][w];
    int pc = __popc(bits);
    int incl = pc;
    for (int d = 1; d < 64; d <<= 1) {
      int u = __shfl_up(incl, d, 64);
      if (lane >= d) incl += u;
    }
    int bpos = ktot + incl - pc;
    while (bits) {
      int b = __builtin_ctz(bits);
      bits &= bits - 1;
      if (bpos < CAP) stj[wave][bpos] = (unsigned short)(w * 32 + b);
      ++bpos;
    }
    ktot += __shfl(incl, 63, 64);
  }

  int k = ktot > CAP ? CAP : ktot;
  for (int s2 = lane; s2 < k; s2 += 64) {
    int j = stj[wave][s2];
    int o = ro + s2;
    if ((unsigned)o < MAXP) {
      float xj = pos[3 * j], yj = pos[3 * j + 1], zj = pos[3 * j + 2];
      float ds = sqrtf(d2_direct(pi.x, pi.y, pi.z, xj, yj, zj));
      ((float2*)out)[o] = make_float2((float)rid, (float)j);  // interleaved pair
      out[2 * MAXP + o] = (rid < j) ? 1.0f : 0.0f;            // buffer_scales
      out[3 * MAXP + o] = ds;                                 // ds
    }
  }
}

extern "C" void kernel_launch(void* const* d_in, const int* in_sizes, int n_in,
                              void* d_out, int out_size, void* d_ws, size_t ws_size,
                              hipStream_t stream) {
  const float* pos = (const float*)d_in[0];  // float32 [8192,3]
  float* out = (float*)d_out;                // float32 [4*MAXP]
  float* ws = (float*)d_ws;

  nl_prep<<<64, 1024, 0, stream>>>(pos, out, ws);
  nl_count<<<2048, 256, 0, stream>>>(ws);
  nl_write<<<2048, 256, 0, stream>>>(pos, out, ws);
}

// Round 9
// 104.115 us; speedup vs baseline: 1.0102x; 1.0102x over previous
//
#include <hip/hip_runtime.h>

#define MAXP 1048576           // static pair bound (MAX_PAIRS)
#define NATOMS 8192
#define D2_CUT 0x1.8ffffep+4f  // fl(sqrt(s))<5  <=>  s < 25-2^-19
#define CINV 0.175f            // 7/40: 7^3=343 cells, width 5.714 > 5.0004 (conservative)
#define CAP 192                // max hits/row (avg ~67, observed max ~115)

// d_ws layout (float offsets). Total ~948 KB; ws_size >= 268 MB (the harness
// poisons 262144 KB per iteration -> proven lower bound).
#define W_SORTPOS 0            // float4[8192] cell-sorted (x,y,z,sq)
#define W_SORTID  32768        // u16[8192] sorted slot -> original atom id
#define W_ROWCNT  36864        // int[8192] per-row hit counts (reference counts)
#define W_GRPSUM  45056        // int[128] per-64-row-group sums (padded to 512)
#define W_CELLOFF 45568        // int[344], padded to 512
#define W_JBUF    46080        // u16[8192][CAP] ordered j-lists (3 MB)

__device__ __forceinline__ float sq3_nc(float x, float y, float z) {
#pragma clang fp contract(off)
  float a = x * x;
  float b = y * y;
  float c = z * z;
  return (a + b) + c;
}

// mask per _pairwise_dist: sq_i + sq_j - 2*(x @ x.T); BLAS K=3 FMA chain (bit-exact, proven)
__device__ __forceinline__ float d2_gram(float xi, float yi, float zi, float sqi,
                                         float xj, float yj, float zj, float sqj) {
#pragma clang fp contract(off)
  float g = xi * xj;
  g = __builtin_fmaf(yi, yj, g);
  g = __builtin_fmaf(zi, zj, g);
  float t = sqi + sqj;
  float d2 = t - 2.0f * g;
  return d2;
}

__device__ __forceinline__ float d2_direct(float xi, float yi, float zi,
                                           float xj, float yj, float zj) {
#pragma clang fp contract(off)
  float dx = xj - xi;
  float dy = yj - yi;
  float dz = zj - zi;
  float a = dx * dx;
  float b = dy * dy;
  float c = dz * dz;
  return (a + b) + c;
}

__device__ __forceinline__ int cellco(float v) {
  int c = (int)(v * CINV);
  return c < 0 ? 0 : (c > 6 ? 6 : c);
}

// K0: zero 16.8 MB output (padding must be exactly 0) + zero grpsum.
__global__ __launch_bounds__(256) void nl_pack(float* __restrict__ out,
                                               float* __restrict__ ws) {
  const int gtid = blockIdx.x * 256 + threadIdx.x;  // 65536 threads
  float4* o4 = (float4*)out;                        // 4*MAXP floats = 1,048,576 float4
#pragma unroll
  for (int k = 0; k < 16; ++k)
    o4[k * 65536 + gtid] = make_float4(0.f, 0.f, 0.f, 0.f);
  if (gtid < 512) ((int*)(ws + W_GRPSUM))[gtid] = 0;
}

// K1: single block: bin + scan + scatter entirely in LDS (r7-proven, ~7us).
__global__ __launch_bounds__(1024) void nl_prep(const float* __restrict__ pos,
                                                float* __restrict__ ws) {
  __shared__ int hcnt[343];
  __shared__ int hoff[344];
  __shared__ int hcur[343];
  __shared__ int s[512];
  const int tid = threadIdx.x;
  if (tid < 343) { hcnt[tid] = 0; hcur[tid] = 0; }
  __syncthreads();

  float x[8], y[8], z[8];
  int cl[8];
#pragma unroll
  for (int k = 0; k < 8; ++k) {
    int a = tid + k * 1024;
    x[k] = pos[3 * a]; y[k] = pos[3 * a + 1]; z[k] = pos[3 * a + 2];
    cl[k] = cellco(x[k]) + 7 * cellco(y[k]) + 49 * cellco(z[k]);
    atomicAdd(&hcnt[cl[k]], 1);
  }
  __syncthreads();

  if (tid < 512) s[tid] = (tid < 343) ? hcnt[tid] : 0;
  __syncthreads();
  for (int off = 1; off < 512; off <<= 1) {
    int v = (tid < 512 && tid >= off) ? s[tid - off] : 0;
    __syncthreads();
    if (tid < 512) s[tid] += v;
    __syncthreads();
  }
  if (tid < 343) hoff[tid] = (tid == 0) ? 0 : s[tid - 1];
  if (tid == 343) hoff[343] = NATOMS;
  __syncthreads();
  if (tid < 344) ((int*)(ws + W_CELLOFF))[tid] = hoff[tid];

  unsigned short* sortid = (unsigned short*)(ws + W_SORTID);
  float4* sortpos = (float4*)(ws + W_SORTPOS);
#pragma unroll
  for (int k = 0; k < 8; ++k) {
    int slot = hoff[cl[k]] + atomicAdd(&hcur[cl[k]], 1);
    sortid[slot] = (unsigned short)(tid + k * 1024);
    sortpos[slot] = make_float4(x[k], y[k], z[k], sq3_nc(x[k], y[k], z[k]));
  }
}

// K2: DETECT (single candidate scan — replaces count AND write's re-scan).
// r8-proven body: per-slot wave, strip walk, bitmap marked by ORIGINAL j
// (order-independent), clear self bit, word-ascending extraction (= reference
// j order). NEW: spill the ordered j-list to ws jbuf + rowcnt + grpsum.
// GRID 2048 x 256, 8 waves/SIMD.
__global__ __launch_bounds__(256, 8) void nl_detect(float* __restrict__ ws) {
  __shared__ unsigned int bmap[4][256];    // 8192 bits per wave (wave-private)
  __shared__ unsigned short stj[4][CAP];   // ascending j-list per wave
  const int lane = threadIdx.x & 63;
  const int wave = threadIdx.x >> 6;
  const int slot = blockIdx.x * 4 + wave;  // sorted slot 0..8191

  const float4* __restrict__ sp4 = (const float4*)(ws + W_SORTPOS);
  const unsigned short* __restrict__ sid = (const unsigned short*)(ws + W_SORTID);
  const int* __restrict__ celloff = (const int*)(ws + W_CELLOFF);
  int* rowcnt = (int*)(ws + W_ROWCNT);
  int* grpsum = (int*)(ws + W_GRPSUM);
  unsigned short* jbuf = (unsigned short*)(ws + W_JBUF);

#pragma unroll
  for (int q = 0; q < 4; ++q) bmap[wave][lane + 64 * q] = 0u;

  const float4 pi = sp4[slot];  // bit-identical to pos-derived (x,y,z,sq)
  const int rid = sid[slot];
  int cx = cellco(pi.x), cy = cellco(pi.y), cz = cellco(pi.z);
  int x0 = max(cx - 1, 0), x1 = min(cx + 1, 6);
  int y0 = max(cy - 1, 0), y1 = min(cy + 1, 6);
  int z0 = max(cz - 1, 0), z1 = min(cz + 1, 6);

  for (int icz = z0; icz <= z1; ++icz)
    for (int icy = y0; icy <= y1; ++icy) {
      int cb = 7 * icy + 49 * icz;
      int st = celloff[cb + x0];
      int en = celloff[cb + x1 + 1];
      for (int bb = st; bb < en; bb += 64) {
        int t = bb + lane;
        bool v = t < en;
        int t2 = v ? t : (en - 1);  // clamp: valid slot; pred killed by v
        float4 p = sp4[t2];
        int jd = sid[t2];
        float d2 = d2_gram(pi.x, pi.y, pi.z, pi.w, p.x, p.y, p.z, p.w);
        if (v && d2 < D2_CUT)
          atomicOr(&bmap[wave][jd >> 5], 1u << (jd & 31));
      }
    }
  if (lane == 0)  // self always marked (d2_self ~ ±eps < cut, proven); clear it
    atomicAnd(&bmap[wave][rid >> 5], ~(1u << (rid & 31)));

  // extract in ascending j: 4 segments of 64 words; popcount prefix (proven)
  int ktot = 0;
#pragma unroll
  for (int seg = 0; seg < 4; ++seg) {
    int w = seg * 64 + lane;
    unsigned bits = bmap[wave][w];
    int pc = __popc(bits);
    int incl = pc;
    for (int d = 1; d < 64; d <<= 1) {
      int u = __shfl_up(incl, d, 64);
      if (lane >= d) incl += u;
    }
    int bpos = ktot + incl - pc;
    while (bits) {
      int b = __builtin_ctz(bits);
      bits &= bits - 1;
      if (bpos < CAP) stj[wave][bpos] = (unsigned short)(w * 32 + b);
      ++bpos;
    }
    ktot += __shfl(incl, 63, 64);
  }

  int k = ktot > CAP ? CAP : ktot;
  for (int s2 = lane; s2 < k; s2 += 64)
    jbuf[slot * CAP + s2] = stj[wave][s2];
  if (lane == 0) {
    rowcnt[rid] = ktot;                 // reference per-row count (uncapped)
    atomicAdd(&grpsum[rid >> 6], ktot); // 64-row group partial (r8-proven)
  }
}

// K3: EMIT. One wave per sorted slot. Inline exclusive row offset from
// grpsum + rowcnt (r8-proven, == old scan), then read the ordered j-list and
// write pairs/scales/ds with the bit-exact d2_direct+sqrtf path on raw pos.
__global__ __launch_bounds__(256, 8) void nl_emit(const float* __restrict__ pos,
                                                  float* __restrict__ out,
                                                  const float* __restrict__ ws) {
  const int lane = threadIdx.x & 63;
  const int wave = threadIdx.x >> 6;
  const int slot = blockIdx.x * 4 + wave;  // sorted slot 0..8191

  const float4* __restrict__ sp4 = (const float4*)(ws + W_SORTPOS);
  const unsigned short* __restrict__ sid = (const unsigned short*)(ws + W_SORTID);
  const int* __restrict__ rowcnt = (const int*)(ws + W_ROWCNT);
  const int* __restrict__ grpsum = (const int*)(ws + W_GRPSUM);
  const unsigned short* __restrict__ jbuf = (const unsigned short*)(ws + W_JBUF);

  const float4 pi = sp4[slot];
  const int rid = sid[slot];

  // inline exclusive row offset (r8-proven):
  //   ro = sum_{g < rid>>6} grpsum[g] + sum_{t in [rid&~63, rid)} rowcnt[t]
  const int G = rid >> 6;
  int pre = ((lane < G) ? grpsum[lane] : 0) +
            ((lane + 64 < G) ? grpsum[lane + 64] : 0) +
            ((lane < (rid & 63)) ? rowcnt[(rid & ~63) + lane] : 0);
  for (int off = 32; off > 0; off >>= 1) pre += __shfl_down(pre, off, 64);
  const int ro = __shfl(pre, 0, 64);

  int k = rowcnt[rid];
  if (k > CAP) k = CAP;
  for (int s2 = lane; s2 < k; s2 += 64) {
    int j = jbuf[slot * CAP + s2];
    int o = ro + s2;
    if ((unsigned)o < MAXP) {
      float xj = pos[3 * j], yj = pos[3 * j + 1], zj = pos[3 * j + 2];
      float ds = sqrtf(d2_direct(pi.x, pi.y, pi.z, xj, yj, zj));
      ((float2*)out)[o] = make_float2((float)rid, (float)j);  // interleaved pair
      out[2 * MAXP + o] = (rid < j) ? 1.0f : 0.0f;            // buffer_scales
      out[3 * MAXP + o] = ds;                                 // ds
    }
  }
}

extern "C" void kernel_launch(void* const* d_in, const int* in_sizes, int n_in,
                              void* d_out, int out_size, void* d_ws, size_t ws_size,
                              hipStream_t stream) {
  const float* pos = (const float*)d_in[0];  // float32 [8192,3]
  float* out = (float*)d_out;                // float32 [4*MAXP]
  float* ws = (float*)d_ws;

  nl_pack<<<256, 256, 0, stream>>>(out, ws);
  nl_prep<<<1, 1024, 0, stream>>>(pos, ws);
  nl_detect<<<2048, 256, 0, stream>>>(ws);
  nl_emit<<<2048, 256, 0, stream>>>(pos, out, ws);
}